// Round 4
// baseline (617.151 us; speedup 1.0000x reference)
//
#include <hip/hip_runtime.h>

#define CH 128
#define MM 64
#define BB 128
#define NN 4096
#define KSPLIT 16
#define KCHUNK (NN / KSPLIT)   // 256

// ---------------------------------------------------------------------------
// Kernel 1: partial[b][ks][m][c] = sum_{k in chunk ks} U[b][k][m] * h[b*N+k][c]
// grid: BB*KSPLIT = 2048 blocks, 128 threads (2 waves: m-halves).
// lane = c-pair (float2 h, coalesced); u via wave-uniform s_load (SGPR operand).
// No LDS, no barriers. h row read by both waves -> 2nd hits L1 (same CU).
// ---------------------------------------------------------------------------
__global__ __launch_bounds__(128) void k1_uth(const float* __restrict__ U,
                                              const float* __restrict__ h,
                                              float* __restrict__ hhp) {
    const int tid  = threadIdx.x;
    const int lane = tid & 63;
    const int wv   = __builtin_amdgcn_readfirstlane(tid >> 6);  // 0/1: m-half
    const int bid  = blockIdx.x;
    const int b    = bid >> 4;       // KSPLIT = 16
    const int ks   = bid & 15;
    const int k0   = ks * KCHUNK;

    const float* hp = h + ((size_t)b * NN + k0) * CH + lane * 2;
    const float* up = U + ((size_t)b * NN + k0) * MM + wv * 32;   // uniform base

    float2 acc[32];
    #pragma unroll
    for (int j = 0; j < 32; ++j) acc[j] = make_float2(0.f, 0.f);

    // h prefetch ring, depth 4
    float2 hr[4];
    #pragma unroll
    for (int p = 0; p < 4; ++p)
        hr[p] = *(const float2*)(hp + (size_t)p * CH);

    #pragma unroll 1
    for (int k = 0; k < KCHUNK; k += 4) {
        #pragma unroll
        for (int q = 0; q < 4; ++q) {
            const float2 hv = hr[q];
            const int kn = k + q + 4;
            const int kp = (kn < KCHUNK) ? kn : 0;        // uniform guard
            hr[q] = *(const float2*)(hp + (size_t)kp * CH);
            const float* uq = up + (size_t)(k + q) * MM;  // uniform
            #pragma unroll
            for (int j = 0; j < 32; ++j) {
                const float uj = uq[j];                    // s_load (uniform)
                acc[j].x += uj * hv.x;
                acc[j].y += uj * hv.y;
            }
        }
    }

    float* dst = hhp + ((size_t)(b * KSPLIT + ks) * MM + wv * 32) * CH + lane * 2;
    #pragma unroll
    for (int j = 0; j < 32; ++j)
        *(float2*)(dst + (size_t)j * CH) = acc[j];
}

// ---------------------------------------------------------------------------
// Kernel 2: out_hat[b][m][o] = sum_c (sum_ks partial[b][ks][m][c]) * W[m][c][o]
// grid: (MM, BB/16) = (64, 8), 256 threads.
// ---------------------------------------------------------------------------
__global__ __launch_bounds__(256) void k2_mix(const float* __restrict__ hhp,
                                              const float* __restrict__ W,
                                              float* __restrict__ out_hat) {
    __shared__ float hs[16][CH];     // 8 KB
    const int tid  = threadIdx.x;
    const int o    = tid & 127;
    const int half = tid >> 7;       // 0/1 -> batches [0..8) / [8..16)
    const int m    = blockIdx.x;
    const int b0   = blockIdx.y * 16;

    #pragma unroll
    for (int i = 0; i < 8; ++i) {
        const int b = b0 + half * 8 + i;
        const float* src = hhp + ((size_t)(b * KSPLIT) * MM + m) * CH + o;
        float s = 0.f;
        #pragma unroll
        for (int ksi = 0; ksi < KSPLIT; ++ksi)
            s += src[(size_t)ksi * MM * CH];
        hs[half * 8 + i][o] = s;
    }
    __syncthreads();

    float acc[8];
    #pragma unroll
    for (int i = 0; i < 8; ++i) acc[i] = 0.f;

    const float* Wm = W + (size_t)m * CH * CH;
    for (int c = 0; c < CH; ++c) {
        const float w = Wm[c * CH + o];
        #pragma unroll
        for (int i = 0; i < 8; ++i) acc[i] += hs[half * 8 + i][c] * w;
    }

    #pragma unroll
    for (int i = 0; i < 8; ++i)
        out_hat[((size_t)(b0 + half * 8 + i) * MM + m) * CH + o] = acc[i];
}

// ---------------------------------------------------------------------------
// Kernel 3: out[b][n][o] = sum_m U[b][n][m] * out_hat[b][m][o]
// grid: (NN/128, BB) = (32, 128), 256 threads (4 waves x 32 n-rows each).
// lane = o-pair; out_hat[b] staged in LDS (1 ds_read_b64 per m-step);
// u[n][m] via wave-uniform s_load (K$ line reused across 16 m-steps).
// ---------------------------------------------------------------------------
__global__ __launch_bounds__(256) void k3_back(const float* __restrict__ U,
                                               const float* __restrict__ out_hat,
                                               float* __restrict__ out) {
    __shared__ float oh[MM * CH];    // 32 KB

    const int tid  = threadIdx.x;
    const int lane = tid & 63;
    const int wv   = __builtin_amdgcn_readfirstlane(tid >> 6);  // 0..3
    const int n0   = blockIdx.x * 128;
    const int b    = blockIdx.y;

    // stage out_hat[b]: 8192 floats, linear float4 (L2-hot, reused 32x per b)
    {
        const float4* src = (const float4*)(out_hat + (size_t)b * MM * CH);
        float4* dst = (float4*)oh;
        #pragma unroll
        for (int i = 0; i < 8; ++i)
            dst[tid + i * 256] = src[tid + i * 256];
    }
    __syncthreads();

    const float* uptr = U + ((size_t)b * NN + n0 + wv * 32) * MM;  // uniform base

    float2 acc[32];
    #pragma unroll
    for (int j = 0; j < 32; ++j) acc[j] = make_float2(0.f, 0.f);

    #pragma unroll 2
    for (int m = 0; m < MM; ++m) {
        const float2 ohv = *(const float2*)&oh[m * CH + lane * 2];  // ds_read_b64
        #pragma unroll
        for (int j = 0; j < 32; ++j) {
            const float uj = uptr[(size_t)j * MM + m];   // s_load (uniform)
            acc[j].x += uj * ohv.x;
            acc[j].y += uj * ohv.y;
        }
    }

    float* dst = out + ((size_t)b * NN + n0 + wv * 32) * CH + lane * 2;
    #pragma unroll
    for (int j = 0; j < 32; ++j)
        *(float2*)(dst + (size_t)j * CH) = acc[j];
}

// ---------------------------------------------------------------------------
extern "C" void kernel_launch(void* const* d_in, const int* in_sizes, int n_in,
                              void* d_out, int out_size, void* d_ws, size_t ws_size,
                              hipStream_t stream) {
    const float* h = (const float*)d_in[0];   // [B*N, C]
    const float* U = (const float*)d_in[1];   // [B, N, M]
    const float* W = (const float*)d_in[2];   // [M, C, C]
    float* out = (float*)d_out;

    // partials live in d_out (67 MB of its 268 MB); k3 overwrites all of d_out.
    float* hhp     = (float*)d_out;           // [B*KSPLIT, M, C]
    float* out_hat = (float*)d_ws;            // [B, M, C] = 4 MB

    k1_uth<<<BB * KSPLIT, 128, 0, stream>>>(U, h, hhp);
    k2_mix<<<dim3(MM, BB / 16), 256, 0, stream>>>(hhp, W, out_hat);
    k3_back<<<dim3(NN / 128, BB), 256, 0, stream>>>(U, out_hat, out);
}

// Round 6
// 272.950 us; speedup vs baseline: 2.2610x; 2.2610x over previous
//
#include <hip/hip_runtime.h>

#define CH 128
#define MM 64
#define BB 128
#define NN 4096
#define KSPLIT 8
#define KCHUNK (NN / KSPLIT)   // 512
#define KU 8
#define NIT (KCHUNK / KU)      // 64

#define AS1(p) ((const __attribute__((address_space(1))) void*)(p))
#define AS3(p) ((__attribute__((address_space(3))) void*)(p))

__device__ __forceinline__ void gl_lds16(const float* g, float* l) {
    __builtin_amdgcn_global_load_lds(AS1(g), AS3(l), 16, 0, 0);
}

// ---------------------------------------------------------------------------
// Kernel 1: partial[b][ks][m][c] = sum_{k in chunk ks} U[b][k][m] * h[b*N+k][c]
// grid: BB*KSPLIT = 1024 blocks, 128 threads (2 waves). Thread: 8m x 8c.
// Ratio 64 FMA-instr : 4 ds_read_b128 (was 32:3) -> LDS pipe oversub 1.4x.
// ---------------------------------------------------------------------------
__global__ __launch_bounds__(128) void k1_uth(const float* __restrict__ U,
                                              const float* __restrict__ h,
                                              float* __restrict__ hhp) {
    // panel: [0..511] = U 8x64, [512..1535] = h 8x128
    __shared__ float panel[2][1536];   // 12 KB

    const int tid = threadIdx.x;
    const int bid = blockIdx.x;
    const int b   = bid >> 3;        // KSPLIT = 8
    const int ks  = bid & 7;
    const int k0  = ks * KCHUNK;

    const int mt = tid >> 4;         // 0..7 -> m = mt*8 .. +7
    const int ct = tid & 15;         // c in {ct*4..+3} and {64+ct*4..+3}

    const float* Ub = U + ((size_t)b * NN + k0) * MM;
    const float* hb = h + ((size_t)b * NN + k0) * CH;

    float acc[8][8];
    #pragma unroll
    for (int i = 0; i < 8; ++i)
        #pragma unroll
        for (int j = 0; j < 8; ++j) acc[i][j] = 0.f;

    auto stage = [&](int p, int it) {
        const float* us = Ub + (size_t)it * KU * MM;   // 512 floats
        const float* hs = hb + (size_t)it * KU * CH;   // 1024 floats
        gl_lds16(us + tid * 4,       &panel[p][tid * 4]);
        gl_lds16(hs + tid * 4,       &panel[p][512 + tid * 4]);
        gl_lds16(hs + 512 + tid * 4, &panel[p][1024 + tid * 4]);
    };

    auto compute = [&](const float* __restrict__ P) {
        #pragma unroll
        for (int ku = 0; ku < KU; ++ku) {
            float4 u0 = *(const float4*)&P[ku * 64 + mt * 8];
            float4 u1 = *(const float4*)&P[ku * 64 + mt * 8 + 4];
            float4 h0 = *(const float4*)&P[512 + ku * 128 + ct * 4];
            float4 h1 = *(const float4*)&P[512 + ku * 128 + 64 + ct * 4];
            float u[8]  = {u0.x, u0.y, u0.z, u0.w, u1.x, u1.y, u1.z, u1.w};
            float hv[8] = {h0.x, h0.y, h0.z, h0.w, h1.x, h1.y, h1.z, h1.w};
            #pragma unroll
            for (int i = 0; i < 8; ++i)
                #pragma unroll
                for (int j = 0; j < 8; ++j)
                    acc[i][j] += u[i] * hv[j];
        }
    };

    stage(0, 0);
    #pragma unroll 1
    for (int it = 0; it < NIT - 1; ++it) {
        stage((it + 1) & 1, it + 1);
        asm volatile("s_waitcnt vmcnt(3)" ::: "memory");   // cur panel landed
        __builtin_amdgcn_s_barrier();
        __builtin_amdgcn_sched_barrier(0);
        compute(panel[it & 1]);
        __builtin_amdgcn_s_barrier();
    }
    asm volatile("s_waitcnt vmcnt(0)" ::: "memory");
    __builtin_amdgcn_s_barrier();
    __builtin_amdgcn_sched_barrier(0);
    compute(panel[(NIT - 1) & 1]);

    float* dst = hhp + ((size_t)(b * KSPLIT + ks) * MM + mt * 8) * CH;
    #pragma unroll
    for (int i = 0; i < 8; ++i) {
        *(float4*)&dst[i * CH + ct * 4] =
            make_float4(acc[i][0], acc[i][1], acc[i][2], acc[i][3]);
        *(float4*)&dst[i * CH + 64 + ct * 4] =
            make_float4(acc[i][4], acc[i][5], acc[i][6], acc[i][7]);
    }
}

// ---------------------------------------------------------------------------
// Kernel 2: out_hat[b][m][o] = sum_c (sum_ks partial[b][ks][m][c]) * W[m][c][o]
// grid: (MM, BB/16) = (64, 8), 256 threads.
// ---------------------------------------------------------------------------
__global__ __launch_bounds__(256) void k2_mix(const float* __restrict__ hhp,
                                              const float* __restrict__ W,
                                              float* __restrict__ out_hat) {
    __shared__ float hs[16][CH];     // 8 KB
    const int tid  = threadIdx.x;
    const int o    = tid & 127;
    const int half = tid >> 7;
    const int m    = blockIdx.x;
    const int b0   = blockIdx.y * 16;

    #pragma unroll
    for (int i = 0; i < 8; ++i) {
        const int b = b0 + half * 8 + i;
        const float* src = hhp + ((size_t)(b * KSPLIT) * MM + m) * CH + o;
        float s = 0.f;
        #pragma unroll
        for (int ksi = 0; ksi < KSPLIT; ++ksi)
            s += src[(size_t)ksi * MM * CH];
        hs[half * 8 + i][o] = s;
    }
    __syncthreads();

    float acc[8];
    #pragma unroll
    for (int i = 0; i < 8; ++i) acc[i] = 0.f;

    const float* Wm = W + (size_t)m * CH * CH;
    for (int c = 0; c < CH; ++c) {
        const float w = Wm[c * CH + o];
        #pragma unroll
        for (int i = 0; i < 8; ++i) acc[i] += hs[half * 8 + i][c] * w;
    }

    #pragma unroll
    for (int i = 0; i < 8; ++i)
        out_hat[((size_t)(b0 + half * 8 + i) * MM + m) * CH + o] = acc[i];
}

// ---------------------------------------------------------------------------
// Kernel 3: out[b][n][o] = sum_m U[b][n][m] * out_hat[b][m][o]
// grid: (NN/128, BB) = (32, 128), 256 threads. Thread: 8n x 8o.
// U staged transposed (stride 132: 16B-aligned rows, banks rotate by 4).
// Ratio 64 FMA-instr : 4 b128 per m-step.
// ---------------------------------------------------------------------------
__global__ __launch_bounds__(256) void k3_back(const float* __restrict__ U,
                                               const float* __restrict__ out_hat,
                                               float* __restrict__ out) {
    __shared__ float oh[MM * CH];    // 32 KB
    __shared__ float Ut[MM][132];    // 33.8 KB

    const int tid = threadIdx.x;
    const int n0  = blockIdx.x * 128;
    const int b   = blockIdx.y;

    // stage out_hat[b]: 8192 floats, linear float4
    {
        const float4* src = (const float4*)(out_hat + (size_t)b * MM * CH);
        float4* dst = (float4*)oh;
        #pragma unroll
        for (int i = 0; i < 8; ++i)
            dst[tid + i * 256] = src[tid + i * 256];
    }
    // stage U^T: thread t covers row r = t>>1, m-half = (t&1)*32 (32 floats)
    {
        const int r    = tid >> 1;
        const int mh   = (tid & 1) * 32;
        const float* s = U + ((size_t)b * NN + n0 + r) * MM + mh;
        #pragma unroll
        for (int q = 0; q < 8; ++q) {
            float4 v = *(const float4*)(s + q * 4);
            Ut[mh + q * 4 + 0][r] = v.x;
            Ut[mh + q * 4 + 1][r] = v.y;
            Ut[mh + q * 4 + 2][r] = v.z;
            Ut[mh + q * 4 + 3][r] = v.w;
        }
    }
    __syncthreads();

    const int nt = tid >> 4;    // 0..15 -> n = nt*8 .. +7
    const int ot = tid & 15;    // o in {ot*4..+3} and {64+ot*4..+3}

    float acc[8][8];
    #pragma unroll
    for (int i = 0; i < 8; ++i)
        #pragma unroll
        for (int j = 0; j < 8; ++j) acc[i][j] = 0.f;

    #pragma unroll 4
    for (int m = 0; m < MM; ++m) {
        float4 u0 = *(const float4*)&Ut[m][nt * 8];
        float4 u1 = *(const float4*)&Ut[m][nt * 8 + 4];
        float4 h0 = *(const float4*)&oh[m * CH + ot * 4];
        float4 h1 = *(const float4*)&oh[m * CH + 64 + ot * 4];
        float u[8]  = {u0.x, u0.y, u0.z, u0.w, u1.x, u1.y, u1.z, u1.w};
        float hv[8] = {h0.x, h0.y, h0.z, h0.w, h1.x, h1.y, h1.z, h1.w};
        #pragma unroll
        for (int i = 0; i < 8; ++i)
            #pragma unroll
            for (int j = 0; j < 8; ++j)
                acc[i][j] += u[i] * hv[j];
    }

    float* dst = out + ((size_t)b * NN + n0 + nt * 8) * CH;
    #pragma unroll
    for (int i = 0; i < 8; ++i) {
        *(float4*)&dst[i * CH + ot * 4] =
            make_float4(acc[i][0], acc[i][1], acc[i][2], acc[i][3]);
        *(float4*)&dst[i * CH + 64 + ot * 4] =
            make_float4(acc[i][4], acc[i][5], acc[i][6], acc[i][7]);
    }
}

// ---------------------------------------------------------------------------
extern "C" void kernel_launch(void* const* d_in, const int* in_sizes, int n_in,
                              void* d_out, int out_size, void* d_ws, size_t ws_size,
                              hipStream_t stream) {
    const float* h = (const float*)d_in[0];   // [B*N, C]
    const float* U = (const float*)d_in[1];   // [B, N, M]
    const float* W = (const float*)d_in[2];   // [M, C, C]
    float* out = (float*)d_out;

    // partials live in d_out (34 MB of its 268 MB); k3 overwrites all of d_out.
    float* hhp     = (float*)d_out;           // [B*KSPLIT, M, C]
    float* out_hat = (float*)d_ws;            // [B, M, C] = 4 MB

    k1_uth<<<BB * KSPLIT, 128, 0, stream>>>(U, h, hhp);
    k2_mix<<<dim3(MM, BB / 16), 256, 0, stream>>>(hhp, W, out_hat);
    k3_back<<<dim3(NN / 128, BB), 256, 0, stream>>>(U, out_hat, out);
}

// Round 7
// 239.863 us; speedup vs baseline: 2.5729x; 1.1379x over previous
//
#include <hip/hip_runtime.h>

#define CH 128
#define MM 64
#define BB 128
#define NN 4096
#define KSPLIT 8
#define KCHUNK (NN / KSPLIT)   // 512
#define KU 8
#define NIT (KCHUNK / KU)      // 64

#define AS1(p) ((const __attribute__((address_space(1))) void*)(p))
#define AS3(p) ((__attribute__((address_space(3))) void*)(p))

typedef __bf16 bf16x8 __attribute__((ext_vector_type(8)));
typedef float  f32x4  __attribute__((ext_vector_type(4)));

__device__ __forceinline__ void gl_lds16(const float* g, float* l) {
    __builtin_amdgcn_global_load_lds(AS1(g), AS3(l), 16, 0, 0);
}

// ---------------------------------------------------------------------------
// Kernel 1 (unchanged): partial[b][ks][m][c] = sum_k U[b][k][m]*h[b*N+k][c]
// grid: BB*KSPLIT = 1024 blocks, 128 threads (2 waves). Thread: 8m x 8c.
// ---------------------------------------------------------------------------
__global__ __launch_bounds__(128) void k1_uth(const float* __restrict__ U,
                                              const float* __restrict__ h,
                                              float* __restrict__ hhp) {
    __shared__ float panel[2][1536];   // [0..511]=U 8x64, [512..1535]=h 8x128

    const int tid = threadIdx.x;
    const int bid = blockIdx.x;
    const int b   = bid >> 3;
    const int ks  = bid & 7;
    const int k0  = ks * KCHUNK;

    const int mt = tid >> 4;
    const int ct = tid & 15;

    const float* Ub = U + ((size_t)b * NN + k0) * MM;
    const float* hb = h + ((size_t)b * NN + k0) * CH;

    float acc[8][8];
    #pragma unroll
    for (int i = 0; i < 8; ++i)
        #pragma unroll
        for (int j = 0; j < 8; ++j) acc[i][j] = 0.f;

    auto stage = [&](int p, int it) {
        const float* us = Ub + (size_t)it * KU * MM;
        const float* hs = hb + (size_t)it * KU * CH;
        gl_lds16(us + tid * 4,       &panel[p][tid * 4]);
        gl_lds16(hs + tid * 4,       &panel[p][512 + tid * 4]);
        gl_lds16(hs + 512 + tid * 4, &panel[p][1024 + tid * 4]);
    };

    auto compute = [&](const float* __restrict__ P) {
        #pragma unroll
        for (int ku = 0; ku < KU; ++ku) {
            float4 u0 = *(const float4*)&P[ku * 64 + mt * 8];
            float4 u1 = *(const float4*)&P[ku * 64 + mt * 8 + 4];
            float4 h0 = *(const float4*)&P[512 + ku * 128 + ct * 4];
            float4 h1 = *(const float4*)&P[512 + ku * 128 + 64 + ct * 4];
            float u[8]  = {u0.x, u0.y, u0.z, u0.w, u1.x, u1.y, u1.z, u1.w};
            float hv[8] = {h0.x, h0.y, h0.z, h0.w, h1.x, h1.y, h1.z, h1.w};
            #pragma unroll
            for (int i = 0; i < 8; ++i)
                #pragma unroll
                for (int j = 0; j < 8; ++j)
                    acc[i][j] += u[i] * hv[j];
        }
    };

    stage(0, 0);
    #pragma unroll 1
    for (int it = 0; it < NIT - 1; ++it) {
        stage((it + 1) & 1, it + 1);
        asm volatile("s_waitcnt vmcnt(3)" ::: "memory");
        __builtin_amdgcn_s_barrier();
        __builtin_amdgcn_sched_barrier(0);
        compute(panel[it & 1]);
        __builtin_amdgcn_s_barrier();
    }
    asm volatile("s_waitcnt vmcnt(0)" ::: "memory");
    __builtin_amdgcn_s_barrier();
    __builtin_amdgcn_sched_barrier(0);
    compute(panel[(NIT - 1) & 1]);

    float* dst = hhp + ((size_t)(b * KSPLIT + ks) * MM + mt * 8) * CH;
    #pragma unroll
    for (int i = 0; i < 8; ++i) {
        *(float4*)&dst[i * CH + ct * 4] =
            make_float4(acc[i][0], acc[i][1], acc[i][2], acc[i][3]);
        *(float4*)&dst[i * CH + 64 + ct * 4] =
            make_float4(acc[i][4], acc[i][5], acc[i][6], acc[i][7]);
    }
}

// ---------------------------------------------------------------------------
// Kernel 2: oh[b][m][o] = sum_c (sum_ks partial) * W[m][c][o], stored as
// bf16 in MFMA B-fragment order: ohf[b][(mt*8+ot)*64 + lane][j], where
// m = mt*32 + (lane>>4)*8 + j, o = ot*16 + (lane&15).
// grid: (MM, BB/16) = (64, 8), 256 threads.
// ---------------------------------------------------------------------------
__global__ __launch_bounds__(256) void k2_mix(const float* __restrict__ hhp,
                                              const float* __restrict__ W,
                                              __bf16* __restrict__ ohf) {
    __shared__ float hs[16][CH];
    const int tid  = threadIdx.x;
    const int o    = tid & 127;
    const int half = tid >> 7;
    const int m    = blockIdx.x;
    const int b0   = blockIdx.y * 16;

    #pragma unroll
    for (int i = 0; i < 8; ++i) {
        const int b = b0 + half * 8 + i;
        const float* src = hhp + ((size_t)(b * KSPLIT) * MM + m) * CH + o;
        float s = 0.f;
        #pragma unroll
        for (int ksi = 0; ksi < KSPLIT; ++ksi)
            s += src[(size_t)ksi * MM * CH];
        hs[half * 8 + i][o] = s;
    }
    __syncthreads();

    float acc[8];
    #pragma unroll
    for (int i = 0; i < 8; ++i) acc[i] = 0.f;

    const float* Wm = W + (size_t)m * CH * CH;
    for (int c = 0; c < CH; ++c) {
        const float w = Wm[c * CH + o];
        #pragma unroll
        for (int i = 0; i < 8; ++i) acc[i] += hs[half * 8 + i][c] * w;
    }

    // fragment-layout store
    const int mt      = m >> 5;
    const int m5      = m & 31;
    const int lane_hi = m5 >> 3;
    const int j       = m5 & 7;
    const int ot      = o >> 4;
    const int lane    = lane_hi * 16 + (o & 15);
    const size_t eidx = ((size_t)(mt * 8 + ot) * 64 + lane) * 8 + j;

    #pragma unroll
    for (int i = 0; i < 8; ++i) {
        const int b = b0 + half * 8 + i;
        ohf[(size_t)b * 8192 + eidx] = (__bf16)acc[i];
    }
}

// ---------------------------------------------------------------------------
// Kernel 3: out[b][n][o] = sum_m U[b][n][m] * oh[b][m][o] via bf16 MFMA.
// grid: (NN/64, BB) = (64, 128), 256 threads = 4 waves, wave = 16 n-rows.
// A-frags direct from global U (K=m contiguous); B-frags pre-packed in ohf.
// No LDS, no barriers. D-layout: col=lane&15, row=(lane>>4)*4+reg (m89).
// ---------------------------------------------------------------------------
__global__ __launch_bounds__(256) void k3_back(const float* __restrict__ U,
                                               const __bf16* __restrict__ ohf,
                                               float* __restrict__ out) {
    const int tid  = threadIdx.x;
    const int lane = tid & 63;
    const int wv   = tid >> 6;              // 0..3 -> n-strip
    const int n0   = blockIdx.x * 64;
    const int b    = blockIdx.y;

    // B-fragments for this b: 16 frags x 16 B/lane, coalesced
    const bf16x8* ohfb = (const bf16x8*)(ohf + (size_t)b * 8192);
    bf16x8 bf[2][8];
    #pragma unroll
    for (int mt = 0; mt < 2; ++mt)
        #pragma unroll
        for (int ot = 0; ot < 8; ++ot)
            bf[mt][ot] = ohfb[(mt * 8 + ot) * 64 + lane];

    // A-fragments: lane row = n0 + wv*16 + (lane&15), k-cols contiguous
    const float* arow = U + ((size_t)b * NN + n0 + wv * 16 + (lane & 15)) * MM
                          + ((lane >> 4) << 3);
    bf16x8 af[2];
    #pragma unroll
    for (int mt = 0; mt < 2; ++mt) {
        float4 a0 = *(const float4*)(arow + mt * 32);
        float4 a1 = *(const float4*)(arow + mt * 32 + 4);
        af[mt][0] = (__bf16)a0.x; af[mt][1] = (__bf16)a0.y;
        af[mt][2] = (__bf16)a0.z; af[mt][3] = (__bf16)a0.w;
        af[mt][4] = (__bf16)a1.x; af[mt][5] = (__bf16)a1.y;
        af[mt][6] = (__bf16)a1.z; af[mt][7] = (__bf16)a1.w;
    }

    f32x4 acc[8];
    #pragma unroll
    for (int ot = 0; ot < 8; ++ot) acc[ot] = (f32x4){0.f, 0.f, 0.f, 0.f};

    #pragma unroll
    for (int ot = 0; ot < 8; ++ot) {
        acc[ot] = __builtin_amdgcn_mfma_f32_16x16x32_bf16(af[0], bf[0][ot], acc[ot], 0, 0, 0);
        acc[ot] = __builtin_amdgcn_mfma_f32_16x16x32_bf16(af[1], bf[1][ot], acc[ot], 0, 0, 0);
    }

    // store: D[row=(lane>>4)*4+r][col=lane&15]
    float* dst = out + ((size_t)b * NN + n0 + wv * 16 + (lane >> 4) * 4) * CH + (lane & 15);
    #pragma unroll
    for (int ot = 0; ot < 8; ++ot)
        #pragma unroll
        for (int r = 0; r < 4; ++r)
            dst[(size_t)r * CH + ot * 16] = acc[ot][r];
}

// ---------------------------------------------------------------------------
extern "C" void kernel_launch(void* const* d_in, const int* in_sizes, int n_in,
                              void* d_out, int out_size, void* d_ws, size_t ws_size,
                              hipStream_t stream) {
    const float* h = (const float*)d_in[0];   // [B*N, C]
    const float* U = (const float*)d_in[1];   // [B, N, M]
    const float* W = (const float*)d_in[2];   // [M, C, C]
    float* out = (float*)d_out;

    float*  hhp = (float*)d_out;              // [B*KSPLIT, M, C] partials (34 MB)
    __bf16* ohf = (__bf16*)d_ws;              // [B, 8192] bf16 B-fragments (2 MB)

    k1_uth<<<BB * KSPLIT, 128, 0, stream>>>(U, h, hhp);
    k2_mix<<<dim3(MM, BB / 16), 256, 0, stream>>>(hhp, W, ohf);
    k3_back<<<dim3(NN / 64, BB), 256, 0, stream>>>(U, ohf, out);
}

// Round 8
// 220.901 us; speedup vs baseline: 2.7938x; 1.0858x over previous
//
#include <hip/hip_runtime.h>

#define CH 128
#define MM 64
#define BB 128
#define NN 4096
#define KSPLIT 4
#define KCHUNK (NN / KSPLIT)   // 1024
#define NSTEP (KCHUNK / 32)    // 32

typedef __bf16 bf16x8 __attribute__((ext_vector_type(8)));
typedef float  f32x4  __attribute__((ext_vector_type(4)));

// ---------------------------------------------------------------------------
// Kernel 1 (MFMA): partial[b][ks][m][c] = sum_{n in chunk} U[b][n][m]*h[b][n][c]
// grid: BB*KSPLIT = 512 blocks, 256 threads = 4 waves.
// Wave w: all 4 m-tiles x 2 c-tiles {2w, 2w+1}. Fragments loaded DIRECTLY from
// global as strided dwords (4x64B segments per instr), register ping-pong
// prefetch. No LDS, no barriers. Frag maps: A[row=l&15][k=(l>>4)*8+j],
// B[k=(l>>4)*8+j][col=l&15], D[row=(l>>4)*4+r][col=l&15] (HW-validated R7).
// ---------------------------------------------------------------------------
__global__ __launch_bounds__(256, 2) void k1_uth(const float* __restrict__ U,
                                                 const float* __restrict__ h,
                                                 float* __restrict__ hhp) {
    const int tid  = threadIdx.x;
    const int lane = tid & 63;
    const int wv   = tid >> 6;          // 0..3 -> c-tiles {2wv, 2wv+1}
    const int b    = blockIdx.x >> 2;   // KSPLIT = 4
    const int ks   = blockIdx.x & 3;
    const int k0   = ks * KCHUNK;

    const int l15 = lane & 15;
    const int lk  = (lane >> 4) * 8;    // k-offset within 32

    // A source: U[(b*NN + k0 + lk + step*32 + j)*MM + mt*16 + l15]
    const float* Ua = U + ((size_t)b * NN + k0 + lk) * MM + l15;
    // B source: h[(b*NN + k0 + lk + step*32 + j)*CH + wv*32 + ci*16 + l15]
    const float* ha = h + ((size_t)b * NN + k0 + lk) * CH + wv * 32 + l15;

    float ar[2][4][8];   // A dwords: [buf][m-tile][j]
    float br[2][2][8];   // B dwords: [buf][c-tile][j]

    auto load_step = [&](int buf, int step) {
        const float* ua = Ua + (size_t)step * 32 * MM;
        const float* hb = ha + (size_t)step * 32 * CH;
        #pragma unroll
        for (int mt = 0; mt < 4; ++mt)
            #pragma unroll
            for (int j = 0; j < 8; ++j)
                ar[buf][mt][j] = ua[j * MM + mt * 16];
        #pragma unroll
        for (int ci = 0; ci < 2; ++ci)
            #pragma unroll
            for (int j = 0; j < 8; ++j)
                br[buf][ci][j] = hb[j * CH + ci * 16];
    };

    f32x4 acc[4][2];
    #pragma unroll
    for (int mt = 0; mt < 4; ++mt)
        #pragma unroll
        for (int ci = 0; ci < 2; ++ci)
            acc[mt][ci] = (f32x4){0.f, 0.f, 0.f, 0.f};

    auto compute = [&](int buf) {
        bf16x8 af[4], bfr[2];
        #pragma unroll
        for (int mt = 0; mt < 4; ++mt)
            #pragma unroll
            for (int j = 0; j < 8; ++j)
                af[mt][j] = (__bf16)ar[buf][mt][j];
        #pragma unroll
        for (int ci = 0; ci < 2; ++ci)
            #pragma unroll
            for (int j = 0; j < 8; ++j)
                bfr[ci][j] = (__bf16)br[buf][ci][j];
        #pragma unroll
        for (int mt = 0; mt < 4; ++mt)
            #pragma unroll
            for (int ci = 0; ci < 2; ++ci)
                acc[mt][ci] = __builtin_amdgcn_mfma_f32_16x16x32_bf16(
                    af[mt], bfr[ci], acc[mt][ci], 0, 0, 0);
    };

    load_step(0, 0);
    #pragma unroll 2
    for (int t = 0; t < NSTEP - 1; ++t) {
        load_step((t + 1) & 1, t + 1);   // issue next-step loads first
        compute(t & 1);                  // waitcnt lands at first use
    }
    compute((NSTEP - 1) & 1);

    // store partial: D[row][col] -> h_hat[m][c]
    float* dst = hhp + (size_t)(b * KSPLIT + ks) * MM * CH;
    const int rowbase = (lane >> 4) * 4;
    #pragma unroll
    for (int mt = 0; mt < 4; ++mt)
        #pragma unroll
        for (int ci = 0; ci < 2; ++ci)
            #pragma unroll
            for (int r = 0; r < 4; ++r)
                dst[(size_t)(mt * 16 + rowbase + r) * CH + wv * 32 + ci * 16 + l15] =
                    acc[mt][ci][r];
}

// ---------------------------------------------------------------------------
// Kernel 2: oh[b][m][o] = sum_c (sum_ks partial) * W[m][c][o], stored as
// bf16 in MFMA B-fragment order (same packing HW-validated in R7).
// grid: (MM, BB/16) = (64, 8), 256 threads.
// ---------------------------------------------------------------------------
__global__ __launch_bounds__(256) void k2_mix(const float* __restrict__ hhp,
                                              const float* __restrict__ W,
                                              __bf16* __restrict__ ohf) {
    __shared__ float hs[16][CH];
    const int tid  = threadIdx.x;
    const int o    = tid & 127;
    const int half = tid >> 7;
    const int m    = blockIdx.x;
    const int b0   = blockIdx.y * 16;

    #pragma unroll
    for (int i = 0; i < 8; ++i) {
        const int b = b0 + half * 8 + i;
        const float* src = hhp + ((size_t)(b * KSPLIT) * MM + m) * CH + o;
        float s = 0.f;
        #pragma unroll
        for (int ksi = 0; ksi < KSPLIT; ++ksi)
            s += src[(size_t)ksi * MM * CH];
        hs[half * 8 + i][o] = s;
    }
    __syncthreads();

    float acc[8];
    #pragma unroll
    for (int i = 0; i < 8; ++i) acc[i] = 0.f;

    const float* Wm = W + (size_t)m * CH * CH;
    for (int c = 0; c < CH; ++c) {
        const float w = Wm[c * CH + o];
        #pragma unroll
        for (int i = 0; i < 8; ++i) acc[i] += hs[half * 8 + i][c] * w;
    }

    // fragment-layout store: m = mt*32 + (lane>>4)*8 + j, o = ot*16 + (lane&15)
    const int mt      = m >> 5;
    const int m5      = m & 31;
    const int lane_hi = m5 >> 3;
    const int j       = m5 & 7;
    const int ot      = o >> 4;
    const int lane    = lane_hi * 16 + (o & 15);
    const size_t eidx = ((size_t)(mt * 8 + ot) * 64 + lane) * 8 + j;

    #pragma unroll
    for (int i = 0; i < 8; ++i) {
        const int b = b0 + half * 8 + i;
        ohf[(size_t)b * 8192 + eidx] = (__bf16)acc[i];
    }
}

// ---------------------------------------------------------------------------
// Kernel 3 (unchanged): out[b][n][o] = sum_m U[b][n][m] * oh[b][m][o], MFMA.
// grid: (NN/64, BB) = (64, 128), 256 threads = 4 waves, wave = 16 n-rows.
// ---------------------------------------------------------------------------
__global__ __launch_bounds__(256) void k3_back(const float* __restrict__ U,
                                               const __bf16* __restrict__ ohf,
                                               float* __restrict__ out) {
    const int tid  = threadIdx.x;
    const int lane = tid & 63;
    const int wv   = tid >> 6;
    const int n0   = blockIdx.x * 64;
    const int b    = blockIdx.y;

    const bf16x8* ohfb = (const bf16x8*)(ohf + (size_t)b * 8192);
    bf16x8 bf[2][8];
    #pragma unroll
    for (int mt = 0; mt < 2; ++mt)
        #pragma unroll
        for (int ot = 0; ot < 8; ++ot)
            bf[mt][ot] = ohfb[(mt * 8 + ot) * 64 + lane];

    const float* arow = U + ((size_t)b * NN + n0 + wv * 16 + (lane & 15)) * MM
                          + ((lane >> 4) << 3);
    bf16x8 af[2];
    #pragma unroll
    for (int mt = 0; mt < 2; ++mt) {
        float4 a0 = *(const float4*)(arow + mt * 32);
        float4 a1 = *(const float4*)(arow + mt * 32 + 4);
        af[mt][0] = (__bf16)a0.x; af[mt][1] = (__bf16)a0.y;
        af[mt][2] = (__bf16)a0.z; af[mt][3] = (__bf16)a0.w;
        af[mt][4] = (__bf16)a1.x; af[mt][5] = (__bf16)a1.y;
        af[mt][6] = (__bf16)a1.z; af[mt][7] = (__bf16)a1.w;
    }

    f32x4 acc[8];
    #pragma unroll
    for (int ot = 0; ot < 8; ++ot) acc[ot] = (f32x4){0.f, 0.f, 0.f, 0.f};

    #pragma unroll
    for (int ot = 0; ot < 8; ++ot) {
        acc[ot] = __builtin_amdgcn_mfma_f32_16x16x32_bf16(af[0], bf[0][ot], acc[ot], 0, 0, 0);
        acc[ot] = __builtin_amdgcn_mfma_f32_16x16x32_bf16(af[1], bf[1][ot], acc[ot], 0, 0, 0);
    }

    float* dst = out + ((size_t)b * NN + n0 + wv * 16 + (lane >> 4) * 4) * CH + (lane & 15);
    #pragma unroll
    for (int ot = 0; ot < 8; ++ot)
        #pragma unroll
        for (int r = 0; r < 4; ++r)
            dst[(size_t)r * CH + ot * 16] = acc[ot][r];
}

// ---------------------------------------------------------------------------
extern "C" void kernel_launch(void* const* d_in, const int* in_sizes, int n_in,
                              void* d_out, int out_size, void* d_ws, size_t ws_size,
                              hipStream_t stream) {
    const float* h = (const float*)d_in[0];   // [B*N, C]
    const float* U = (const float*)d_in[1];   // [B, N, M]
    const float* W = (const float*)d_in[2];   // [M, C, C]
    float* out = (float*)d_out;

    float*  hhp = (float*)d_out;              // [B*KSPLIT, M, C] partials (16 MB)
    __bf16* ohf = (__bf16*)d_ws;              // [B, 8192] bf16 B-fragments (2 MB)

    k1_uth<<<BB * KSPLIT, 256, 0, stream>>>(U, h, hhp);
    k2_mix<<<dim3(MM, BB / 16), 256, 0, stream>>>(hhp, W, ohf);
    k3_back<<<dim3(NN / 64, BB), 256, 0, stream>>>(U, ohf, out);
}

// Round 10
// 219.441 us; speedup vs baseline: 2.8124x; 1.0066x over previous
//
#include <hip/hip_runtime.h>

#define CH 128
#define MM 64
#define BB 128
#define NN 4096
#define KSPLIT 4
#define KCHUNK (NN / KSPLIT)   // 1024
#define NSTEP (KCHUNK / 32)    // 32

typedef __bf16 bf16x8 __attribute__((ext_vector_type(8)));
typedef float  f32x4  __attribute__((ext_vector_type(4)));

// ---------------------------------------------------------------------------
// Kernel 1 (MFMA): partial[b][ks][m][c] = sum_{n in chunk} U[b][n][m]*h[b][n][c]
// grid: BB*KSPLIT = 512 blocks, 256 threads = 4 waves.
// Lane-assignment remap for vectorized loads (bijection-invariance, HW-validated
// R7/R8): A-tiles {0,1} give lane r the m-pair {2r,2r+1} (one float2), tiles
// {2,3} the pair {32+2r,33+2r}; B-tiles {2wv,2wv+1} give lane c the c-pair
// {wv*32+2c,+1}. 24 float2 loads/lane/step (was 48 dwords), 128B segments.
// D-store decodes the remap; ci pairs merge into contiguous float2 stores.
// k-slots: canonical k = (l>>4)*8 + j on both A and B -> sum invariant.
// ---------------------------------------------------------------------------
__global__ __launch_bounds__(256, 2) void k1_uth(const float* __restrict__ U,
                                                 const float* __restrict__ h,
                                                 float* __restrict__ hhp) {
    const int tid  = threadIdx.x;
    const int lane = tid & 63;
    const int wv   = tid >> 6;          // 0..3 -> c-tiles {2wv, 2wv+1}
    const int b    = blockIdx.x >> 2;   // KSPLIT = 4
    const int ks   = blockIdx.x & 3;
    const int k0   = ks * KCHUNK;

    const int l15 = lane & 15;
    const int g   = lane >> 4;
    const int lk  = g * 8;              // k-offset within 32

    // A: U[(b*NN + k0 + lk + step*32 + j)*MM + {2*l15, 32+2*l15}]
    const float* Ua = U + ((size_t)b * NN + k0 + lk) * MM + 2 * l15;
    // B: h[(b*NN + k0 + lk + step*32 + j)*CH + wv*32 + 2*l15]
    const float* ha = h + ((size_t)b * NN + k0 + lk) * CH + wv * 32 + 2 * l15;

    float2 ar[2][2][8];   // [buf][m-half][j]
    float2 br[2][8];      // [buf][j]

    auto load_step = [&](int buf, int step) {
        const float* ua = Ua + (size_t)step * 32 * MM;
        const float* hb = ha + (size_t)step * 32 * CH;
        #pragma unroll
        for (int j = 0; j < 8; ++j) {
            ar[buf][0][j] = *(const float2*)(ua + j * MM);
            ar[buf][1][j] = *(const float2*)(ua + j * MM + 32);
        }
        #pragma unroll
        for (int j = 0; j < 8; ++j)
            br[buf][j] = *(const float2*)(hb + j * CH);
    };

    f32x4 acc[4][2];
    #pragma unroll
    for (int t = 0; t < 4; ++t)
        #pragma unroll
        for (int ci = 0; ci < 2; ++ci)
            acc[t][ci] = (f32x4){0.f, 0.f, 0.f, 0.f};

    auto compute = [&](int buf) {
        bf16x8 af[4], bfr[2];
        #pragma unroll
        for (int j = 0; j < 8; ++j) {
            af[0][j]  = (__bf16)ar[buf][0][j].x;   // m = 2r
            af[1][j]  = (__bf16)ar[buf][0][j].y;   // m = 2r+1
            af[2][j]  = (__bf16)ar[buf][1][j].x;   // m = 32+2r
            af[3][j]  = (__bf16)ar[buf][1][j].y;   // m = 33+2r
            bfr[0][j] = (__bf16)br[buf][j].x;      // c = wv*32+2c
            bfr[1][j] = (__bf16)br[buf][j].y;      // c = wv*32+2c+1
        }
        #pragma unroll
        for (int t = 0; t < 4; ++t)
            #pragma unroll
            for (int ci = 0; ci < 2; ++ci)
                acc[t][ci] = __builtin_amdgcn_mfma_f32_16x16x32_bf16(
                    af[t], bfr[ci], acc[t][ci], 0, 0, 0);
    };

    load_step(0, 0);
    #pragma unroll 2
    for (int t = 0; t < NSTEP - 1; ++t) {
        load_step((t + 1) & 1, t + 1);   // issue next-step loads first
        compute(t & 1);                  // waitcnt lands at first use
    }
    compute((NSTEP - 1) & 1);

    // store: D[row=g*4+r][col=l15]; m = (t>>1)*32 + 2*(g*4+r) + (t&1),
    // c = wv*32 + 2*l15 + ci -> ci pair merges into one float2.
    float* dst = hhp + (size_t)(b * KSPLIT + ks) * MM * CH + wv * 32 + 2 * l15;
    #pragma unroll
    for (int t = 0; t < 4; ++t)
        #pragma unroll
        for (int r = 0; r < 4; ++r) {
            const int m = (t >> 1) * 32 + 2 * (g * 4 + r) + (t & 1);
            *(float2*)(dst + (size_t)m * CH) =
                make_float2(acc[t][0][r], acc[t][1][r]);
        }
}

// ---------------------------------------------------------------------------
// Kernel 2 (unchanged from R8): oh[b][m][o] = sum_c (sum_ks partial) * W[m][c][o]
// stored bf16 in MFMA B-fragment order. grid: (MM, BB/16), 256 threads.
// ---------------------------------------------------------------------------
__global__ __launch_bounds__(256) void k2_mix(const float* __restrict__ hhp,
                                              const float* __restrict__ W,
                                              __bf16* __restrict__ ohf) {
    __shared__ float hs[16][CH];
    const int tid  = threadIdx.x;
    const int o    = tid & 127;
    const int half = tid >> 7;
    const int m    = blockIdx.x;
    const int b0   = blockIdx.y * 16;

    #pragma unroll
    for (int i = 0; i < 8; ++i) {
        const int b = b0 + half * 8 + i;
        const float* src = hhp + ((size_t)(b * KSPLIT) * MM + m) * CH + o;
        float s = 0.f;
        #pragma unroll
        for (int ksi = 0; ksi < KSPLIT; ++ksi)
            s += src[(size_t)ksi * MM * CH];
        hs[half * 8 + i][o] = s;
    }
    __syncthreads();

    float acc[8];
    #pragma unroll
    for (int i = 0; i < 8; ++i) acc[i] = 0.f;

    const float* Wm = W + (size_t)m * CH * CH;
    for (int c = 0; c < CH; ++c) {
        const float w = Wm[c * CH + o];
        #pragma unroll
        for (int i = 0; i < 8; ++i) acc[i] += hs[half * 8 + i][c] * w;
    }

    const int mt      = m >> 5;
    const int m5      = m & 31;
    const int lane_hi = m5 >> 3;
    const int j       = m5 & 7;
    const int ot      = o >> 4;
    const int lane    = lane_hi * 16 + (o & 15);
    const size_t eidx = ((size_t)(mt * 8 + ot) * 64 + lane) * 8 + j;

    #pragma unroll
    for (int i = 0; i < 8; ++i) {
        const int b = b0 + half * 8 + i;
        ohf[(size_t)b * 8192 + eidx] = (__bf16)acc[i];
    }
}

// ---------------------------------------------------------------------------
// Kernel 3 (unchanged from R8): out[b][n][o] = sum_m U[b][n][m]*oh[b][m][o], MFMA.
// grid: (NN/64, BB), 256 threads = 4 waves, wave = 16 n-rows.
// ---------------------------------------------------------------------------
__global__ __launch_bounds__(256) void k3_back(const float* __restrict__ U,
                                               const __bf16* __restrict__ ohf,
                                               float* __restrict__ out) {
    const int tid  = threadIdx.x;
    const int lane = tid & 63;
    const int wv   = tid >> 6;
    const int n0   = blockIdx.x * 64;
    const int b    = blockIdx.y;

    const bf16x8* ohfb = (const bf16x8*)(ohf + (size_t)b * 8192);
    bf16x8 bf[2][8];
    #pragma unroll
    for (int mt = 0; mt < 2; ++mt)
        #pragma unroll
        for (int ot = 0; ot < 8; ++ot)
            bf[mt][ot] = ohfb[(mt * 8 + ot) * 64 + lane];

    const float* arow = U + ((size_t)b * NN + n0 + wv * 16 + (lane & 15)) * MM
                          + ((lane >> 4) << 3);
    bf16x8 af[2];
    #pragma unroll
    for (int mt = 0; mt < 2; ++mt) {
        float4 a0 = *(const float4*)(arow + mt * 32);
        float4 a1 = *(const float4*)(arow + mt * 32 + 4);
        af[mt][0] = (__bf16)a0.x; af[mt][1] = (__bf16)a0.y;
        af[mt][2] = (__bf16)a0.z; af[mt][3] = (__bf16)a0.w;
        af[mt][4] = (__bf16)a1.x; af[mt][5] = (__bf16)a1.y;
        af[mt][6] = (__bf16)a1.z; af[mt][7] = (__bf16)a1.w;
    }

    f32x4 acc[8];
    #pragma unroll
    for (int ot = 0; ot < 8; ++ot) acc[ot] = (f32x4){0.f, 0.f, 0.f, 0.f};

    #pragma unroll
    for (int ot = 0; ot < 8; ++ot) {
        acc[ot] = __builtin_amdgcn_mfma_f32_16x16x32_bf16(af[0], bf[0][ot], acc[ot], 0, 0, 0);
        acc[ot] = __builtin_amdgcn_mfma_f32_16x16x32_bf16(af[1], bf[1][ot], acc[ot], 0, 0, 0);
    }

    float* dst = out + ((size_t)b * NN + n0 + wv * 16 + (lane >> 4) * 4) * CH + (lane & 15);
    #pragma unroll
    for (int ot = 0; ot < 8; ++ot)
        #pragma unroll
        for (int r = 0; r < 4; ++r)
            dst[(size_t)r * CH + ot * 16] = acc[ot][r];
}

// ---------------------------------------------------------------------------
extern "C" void kernel_launch(void* const* d_in, const int* in_sizes, int n_in,
                              void* d_out, int out_size, void* d_ws, size_t ws_size,
                              hipStream_t stream) {
    const float* h = (const float*)d_in[0];   // [B*N, C]
    const float* U = (const float*)d_in[1];   // [B, N, M]
    const float* W = (const float*)d_in[2];   // [M, C, C]
    float* out = (float*)d_out;

    float*  hhp = (float*)d_out;              // [B*KSPLIT, M, C] partials (16 MB)
    __bf16* ohf = (__bf16*)d_ws;              // [B, 8192] bf16 B-fragments (2 MB)

    k1_uth<<<BB * KSPLIT, 256, 0, stream>>>(U, h, hhp);
    k2_mix<<<dim3(MM, BB / 16), 256, 0, stream>>>(hhp, W, ohf);
    k3_back<<<dim3(NN / 64, BB), 256, 0, stream>>>(U, ohf, out);
}

// Round 13
// 212.443 us; speedup vs baseline: 2.9050x; 1.0329x over previous
//
#include <hip/hip_runtime.h>

#define CH 128
#define MM 64
#define BB 128
#define NN 4096
#define KSPLIT 4
#define KCHUNK (NN / KSPLIT)   // 1024
#define KSTEP 32
#define NSTEP (KCHUNK / KSTEP) // 32

#define UBUF (KSTEP * MM)      // 2048 floats = 8 KB
#define HBUF (KSTEP * CH)      // 4096 floats = 16 KB
#define BUF  (UBUF + HBUF)     // 6144 floats = 24 KB

typedef __bf16 bf16x8 __attribute__((ext_vector_type(8)));
typedef float  f32x4  __attribute__((ext_vector_type(4)));

#define AS1(p) ((const __attribute__((address_space(1))) void*)(p))
#define AS3(p) ((__attribute__((address_space(3))) void*)(p))

__device__ __forceinline__ void gl_lds16(const float* g, float* l) {
    __builtin_amdgcn_global_load_lds(AS1(g), AS3(l), 16, 0, 0);
}

// ---------------------------------------------------------------------------
// Kernel 1 (MFMA + async-LDS staging): partial[b][ks][m][c] =
//   sum_{n in chunk} U[b][n][m] * h[b][n][c]
// grid: BB*KSPLIT = 512 blocks, 256 thr = 4 waves (wave wv -> c-slice wv*32).
// Staging: global_load_lds (16B), 3 LDS buffers, depth-2 prefetch, counted
// vmcnt(12/6/0) (T3/T4). Fragments read from LDS as float2 -> cvt bf16.
// Remap (HW-validated R10): A-tiles {0,1}: lane r holds m {2r,2r+1}; tiles
// {2,3}: {32+2r,33+2r}; B-tiles {2wv,2wv+1}: lane c holds {wv*32+2c,+1}.
// k-slots canonical k=(l>>4)*8+j on both A and B -> sum invariant.
// ---------------------------------------------------------------------------
__global__ __launch_bounds__(256, 2) void k1_uth(const float* __restrict__ U,
                                                 const float* __restrict__ h,
                                                 float* __restrict__ hhp) {
    __shared__ float lds[3 * BUF];     // 72 KB

    const int tid  = threadIdx.x;
    const int lane = tid & 63;
    const int wv   = tid >> 6;          // 0..3 -> c-tiles {2wv, 2wv+1}
    const int b    = blockIdx.x >> 2;   // KSPLIT = 4
    const int ks   = blockIdx.x & 3;
    const int k0   = ks * KCHUNK;

    const int l15 = lane & 15;
    const int g   = lane >> 4;
    const int lk  = g * 8;              // k-offset within 32

    const float* Ub = U + ((size_t)b * NN + k0) * MM;
    const float* hb = h + ((size_t)b * NN + k0) * CH;

    auto stage = [&](int s, int t) {    // 6 gl_lds16 per thread
        float* dst = &lds[s * BUF];
        const float* us = Ub + (size_t)t * KSTEP * MM;   // 2048 floats
        const float* hs = hb + (size_t)t * KSTEP * CH;   // 4096 floats
        gl_lds16(us + tid * 4,        dst + tid * 4);
        gl_lds16(us + 1024 + tid * 4, dst + 1024 + tid * 4);
        gl_lds16(hs + tid * 4,        dst + UBUF + tid * 4);
        gl_lds16(hs + 1024 + tid * 4, dst + UBUF + 1024 + tid * 4);
        gl_lds16(hs + 2048 + tid * 4, dst + UBUF + 2048 + tid * 4);
        gl_lds16(hs + 3072 + tid * 4, dst + UBUF + 3072 + tid * 4);
    };

    f32x4 acc[4][2];
    #pragma unroll
    for (int t = 0; t < 4; ++t)
        #pragma unroll
        for (int ci = 0; ci < 2; ++ci)
            acc[t][ci] = (f32x4){0.f, 0.f, 0.f, 0.f};

    auto compute = [&](int s) {
        const float* P  = &lds[s * BUF];
        const float* Pa = P + lk * 64 + 2 * l15;
        const float* Pb = P + UBUF + lk * 128 + wv * 32 + 2 * l15;
        bf16x8 af[4], bfr[2];
        #pragma unroll
        for (int j = 0; j < 8; ++j) {
            float2 a0 = *(const float2*)(Pa + j * 64);
            float2 a1 = *(const float2*)(Pa + j * 64 + 32);
            float2 bv = *(const float2*)(Pb + j * 128);
            af[0][j]  = (__bf16)a0.x;   // m = 2r
            af[1][j]  = (__bf16)a0.y;   // m = 2r+1
            af[2][j]  = (__bf16)a1.x;   // m = 32+2r
            af[3][j]  = (__bf16)a1.y;   // m = 33+2r
            bfr[0][j] = (__bf16)bv.x;   // c = wv*32+2c
            bfr[1][j] = (__bf16)bv.y;   // c = wv*32+2c+1
        }
        #pragma unroll
        for (int t = 0; t < 4; ++t)
            #pragma unroll
            for (int ci = 0; ci < 2; ++ci)
                acc[t][ci] = __builtin_amdgcn_mfma_f32_16x16x32_bf16(
                    af[t], bfr[ci], acc[t][ci], 0, 0, 0);
    };

    stage(0, 0);
    stage(1, 1);
    #pragma unroll 1
    for (int t = 0; t < NSTEP; ++t) {
        if (t + 2 < NSTEP) {
            stage((t + 2) % 3, t + 2);                      // depth-2 prefetch
            asm volatile("s_waitcnt vmcnt(12)" ::: "memory"); // stage t landed
        } else if (t + 1 < NSTEP) {
            asm volatile("s_waitcnt vmcnt(6)" ::: "memory");
        } else {
            asm volatile("s_waitcnt vmcnt(0)" ::: "memory");
        }
        __builtin_amdgcn_s_barrier();
        __builtin_amdgcn_sched_barrier(0);
        compute(t % 3);
        __builtin_amdgcn_s_barrier();                       // all done reading t
    }

    // store: D[row=g*4+r][col=l15]; m = (t>>1)*32 + 2*(g*4+r) + (t&1);
    // c = wv*32 + 2*l15 + ci -> ci pair merges into one float2.
    float* dst = hhp + (size_t)(b * KSPLIT + ks) * MM * CH + wv * 32 + 2 * l15;
    #pragma unroll
    for (int t = 0; t < 4; ++t)
        #pragma unroll
        for (int r = 0; r < 4; ++r) {
            const int m = (t >> 1) * 32 + 2 * (g * 4 + r) + (t & 1);
            *(float2*)(dst + (size_t)m * CH) =
                make_float2(acc[t][0][r], acc[t][1][r]);
        }
}

// ---------------------------------------------------------------------------
// Kernel 2 (unchanged from R8/R10): oh[b][m][o] = sum_c (sum_ks partial) *
// W[m][c][o], stored bf16 in MFMA B-fragment order. grid: (MM, BB/16), 256 thr.
// ---------------------------------------------------------------------------
__global__ __launch_bounds__(256) void k2_mix(const float* __restrict__ hhp,
                                              const float* __restrict__ W,
                                              __bf16* __restrict__ ohf) {
    __shared__ float hs[16][CH];
    const int tid  = threadIdx.x;
    const int o    = tid & 127;
    const int half = tid >> 7;
    const int m    = blockIdx.x;
    const int b0   = blockIdx.y * 16;

    #pragma unroll
    for (int i = 0; i < 8; ++i) {
        const int b = b0 + half * 8 + i;
        const float* src = hhp + ((size_t)(b * KSPLIT) * MM + m) * CH + o;
        float s = 0.f;
        #pragma unroll
        for (int ksi = 0; ksi < KSPLIT; ++ksi)
            s += src[(size_t)ksi * MM * CH];
        hs[half * 8 + i][o] = s;
    }
    __syncthreads();

    float acc[8];
    #pragma unroll
    for (int i = 0; i < 8; ++i) acc[i] = 0.f;

    const float* Wm = W + (size_t)m * CH * CH;
    for (int c = 0; c < CH; ++c) {
        const float w = Wm[c * CH + o];
        #pragma unroll
        for (int i = 0; i < 8; ++i) acc[i] += hs[half * 8 + i][c] * w;
    }

    const int mt      = m >> 5;
    const int m5      = m & 31;
    const int lane_hi = m5 >> 3;
    const int j       = m5 & 7;
    const int ot      = o >> 4;
    const int lane    = lane_hi * 16 + (o & 15);
    const size_t eidx = ((size_t)(mt * 8 + ot) * 64 + lane) * 8 + j;

    #pragma unroll
    for (int i = 0; i < 8; ++i) {
        const int b = b0 + half * 8 + i;
        ohf[(size_t)b * 8192 + eidx] = (__bf16)acc[i];
    }
}

// ---------------------------------------------------------------------------
// Kernel 3 (unchanged from R8/R10): out[b][n][o] = sum_m U[b][n][m]*oh[b][m][o].
// grid: (NN/64, BB), 256 threads = 4 waves, wave = 16 n-rows.
// ---------------------------------------------------------------------------
__global__ __launch_bounds__(256) void k3_back(const float* __restrict__ U,
                                               const __bf16* __restrict__ ohf,
                                               float* __restrict__ out) {
    const int tid  = threadIdx.x;
    const int lane = tid & 63;
    const int wv   = tid >> 6;
    const int n0   = blockIdx.x * 64;
    const int b    = blockIdx.y;

    const bf16x8* ohfb = (const bf16x8*)(ohf + (size_t)b * 8192);
    bf16x8 bf[2][8];
    #pragma unroll
    for (int mt = 0; mt < 2; ++mt)
        #pragma unroll
        for (int ot = 0; ot < 8; ++ot)
            bf[mt][ot] = ohfb[(mt * 8 + ot) * 64 + lane];

    const float* arow = U + ((size_t)b * NN + n0 + wv * 16 + (lane & 15)) * MM
                          + ((lane >> 4) << 3);
    bf16x8 af[2];
    #pragma unroll
    for (int mt = 0; mt < 2; ++mt) {
        float4 a0 = *(const float4*)(arow + mt * 32);
        float4 a1 = *(const float4*)(arow + mt * 32 + 4);
        af[mt][0] = (__bf16)a0.x; af[mt][1] = (__bf16)a0.y;
        af[mt][2] = (__bf16)a0.z; af[mt][3] = (__bf16)a0.w;
        af[mt][4] = (__bf16)a1.x; af[mt][5] = (__bf16)a1.y;
        af[mt][6] = (__bf16)a1.z; af[mt][7] = (__bf16)a1.w;
    }

    f32x4 acc[8];
    #pragma unroll
    for (int ot = 0; ot < 8; ++ot) acc[ot] = (f32x4){0.f, 0.f, 0.f, 0.f};

    #pragma unroll
    for (int ot = 0; ot < 8; ++ot) {
        acc[ot] = __builtin_amdgcn_mfma_f32_16x16x32_bf16(af[0], bf[0][ot], acc[ot], 0, 0, 0);
        acc[ot] = __builtin_amdgcn_mfma_f32_16x16x32_bf16(af[1], bf[1][ot], acc[ot], 0, 0, 0);
    }

    float* dst = out + ((size_t)b * NN + n0 + wv * 16 + (lane >> 4) * 4) * CH + (lane & 15);
    #pragma unroll
    for (int ot = 0; ot < 8; ++ot)
        #pragma unroll
        for (int r = 0; r < 4; ++r)
            dst[(size_t)r * CH + ot * 16] = acc[ot][r];
}

// ---------------------------------------------------------------------------
extern "C" void kernel_launch(void* const* d_in, const int* in_sizes, int n_in,
                              void* d_out, int out_size, void* d_ws, size_t ws_size,
                              hipStream_t stream) {
    const float* h = (const float*)d_in[0];   // [B*N, C]
    const float* U = (const float*)d_in[1];   // [B, N, M]
    const float* W = (const float*)d_in[2];   // [M, C, C]
    float* out = (float*)d_out;

    float*  hhp = (float*)d_out;              // [B*KSPLIT, M, C] partials (16 MB)
    __bf16* ohf = (__bf16*)d_ws;              // [B, 8192] bf16 B-fragments (2 MB)

    k1_uth<<<BB * KSPLIT, 256, 0, stream>>>(U, h, hhp);
    k2_mix<<<dim3(MM, BB / 16), 256, 0, stream>>>(hhp, W, ohf);
    k3_back<<<dim3(NN / 64, BB), 256, 0, stream>>>(U, ohf, out);
}